// Round 8
// baseline (289.603 us; speedup 1.0000x reference)
//
#include <hip/hip_runtime.h>
#include <hip/hip_bf16.h>

typedef __attribute__((ext_vector_type(8))) __bf16 bf16x8;
typedef __attribute__((ext_vector_type(4))) __bf16 bf16x4;
typedef __attribute__((ext_vector_type(4))) float  f32x4;

#define MFMA16(a, b, c) __builtin_amdgcn_mfma_f32_16x16x32_bf16((a), (b), (c), 0, 0, 0)

// B=2, S=4096, D=256, P=R=64. Flattened rows g = b*4096 + n (8192 total).
// Wo folded into Wv: Wvo = Wv @ Wo -> attention partials are pre-scale output.
static constexpr size_t OFF_WVT  = 0;                        // bf16 [256][256] (Wvo^T, [n][k])
static constexpr size_t OFF_WLT  = OFF_WVT + 256 * 256 * 2;  // bf16 [64][256]
static constexpr size_t OFF_WRT  = OFF_WLT + 64 * 256 * 2;   // bf16 [64][256]
static constexpr size_t OFF_VT   = 1u << 20;                 // bf16 [2][64][8][256][8] packed V', 4 MiB
static constexpr size_t OFF_L    = 6u << 20;                 // f32  [8192][64]  2 MiB
static constexpr size_t OFF_R    = 8u << 20;                 // f32  [8192][64]  2 MiB
static constexpr size_t OFF_PART = 10u << 20;                // bf16 [4][8192][256] 16 MiB
static constexpr size_t OFF_ZP   = 26u << 20;                // f32  [4][8192]   128 KiB
static constexpr size_t OFF_BAR  = 27u << 20;                // u32  grid-barrier counters

__device__ __forceinline__ float fast_exp2(float x) {
  float e;
  asm("v_exp_f32 %0, %1" : "=v"(e) : "v"(x));
  return e;
}

__device__ __forceinline__ bf16x8 cvt8(float4 a, float4 b) {
  bf16x8 o;
  o[0] = (__bf16)a.x; o[1] = (__bf16)a.y; o[2] = (__bf16)a.z; o[3] = (__bf16)a.w;
  o[4] = (__bf16)b.x; o[5] = (__bf16)b.y; o[6] = (__bf16)b.z; o[7] = (__bf16)b.w;
  return o;
}

// async global->LDS, 16B/lane; lds dst is the wave-uniform base (HW adds 16*lane).
__device__ __forceinline__ void gll16(const __bf16* g, __bf16* l) {
  __builtin_amdgcn_global_load_lds((const __attribute__((address_space(1))) void*)g,
                                   (__attribute__((address_space(3))) void*)l,
                                   16, 0, 0);
}

// Software grid barrier (plain launch; graph-capture-safe, unlike cooperative
// launch). Requires all 512 blocks co-resident: LDS 53.5KB -> 3 blocks/CU
// capacity, launch_bounds(256,2) -> >=2 blocks/CU = 512 slots. Spin MUST be a
// device-scope atomic load (plain/volatile loads can hit stale non-coherent
// XCD-L2). Release fence before arrive; acquire fence after observing.
__device__ __forceinline__ void gbar(unsigned* c, unsigned tgt) {
  __syncthreads();
  if (threadIdx.x == 0) {
    __threadfence();                                  // release my writes
    atomicAdd(c, 1u);                                 // device-scope (m20)
    while (__hip_atomic_load(c, __ATOMIC_RELAXED, __HIP_MEMORY_SCOPE_AGENT) < tgt)
      __builtin_amdgcn_s_sleep(2);
    __threadfence();                                  // acquire (inv L1/L2)
  }
  __syncthreads();
}

// ================= phase 0a: Wvo row k -> Wvt (bf16 [n][k]); 8 indep chains
__device__ __forceinline__ void dev_wvo(int k, int t, const float* __restrict__ Wv,
                                        const float* __restrict__ Wo,
                                        __bf16* __restrict__ Wvt) {
  const float* wvr = Wv + (size_t)k * 256;   // wave-uniform scalar loads
  const float* wo  = Wo + t;                 // coalesced across t
  float a[8] = {};
  for (int j = 0; j < 256; j += 8) {
#pragma unroll
    for (int u = 0; u < 8; ++u) a[u] += wvr[j + u] * wo[(size_t)(j + u) * 256];
  }
  const float s = ((a[0] + a[1]) + (a[2] + a[3])) + ((a[4] + a[5]) + (a[6] + a[7]));
  Wvt[(size_t)t * 256 + k] = (__bf16)s;
}

// ================= phase 0b: Wl/Wr transpose to [n][k] bf16 (1024 elems/block)
__device__ __forceinline__ void dev_tr(int base, int t, const float* __restrict__ Wl,
                                       const float* __restrict__ Wr,
                                       __bf16* __restrict__ Wlt, __bf16* __restrict__ Wrt) {
#pragma unroll
  for (int i = 0; i < 4; ++i) {
    const int idx = base + i * 256 + t;      // 0 .. 32767
    if (idx < 16384) {
      Wlt[(idx & 63) * 256 + (idx >> 6)] = (__bf16)Wl[idx];
    } else {
      const int j = idx - 16384;
      Wrt[(j & 63) * 256 + (j >> 6)] = (__bf16)Wr[j];
    }
  }
}

// ================= phase 1: projection unit u (0..767)
// V' packed [bat][chunk][m8][d][j] (bf16), l, r (fp32). unit%8 == blockIdx%8
// keeps the XCD x-reuse swizzle (all 6 ct-tiles of an rbk share one XCD).
__device__ void dev_proj(int u, int t, char* smem_, const float* __restrict__ x,
                         const __bf16* __restrict__ Wvt, const __bf16* __restrict__ Wlt,
                         const __bf16* __restrict__ Wrt, __bf16* __restrict__ Vt,
                         float* __restrict__ lbuf, float* __restrict__ rbuf) {
  __bf16* vs = (__bf16*)smem_;                     // [m8][d_local][j], 8 KiB
  __syncthreads();                                 // guard vs reuse across units
  const int lane = t & 63, wave = t >> 6;
  const int l16 = lane & 15, quad = lane >> 4;
  const int wr = wave >> 1, wc = wave & 1;
  const int q   = u / 48;
  const int rmd = u - q * 48;
  const int ct  = rmd >> 3;
  const int rbk = q * 8 + (rmd & 7);
  const __bf16* Wt;
  int colbase;
  if (ct < 4)       { Wt = Wvt; colbase = ct * 64; }
  else if (ct == 4) { Wt = Wlt; colbase = 0; }
  else              { Wt = Wrt; colbase = 0; }
  const int row0 = rbk * 64 + wr * 32;
  const int c0   = colbase + wc * 32;
  f32x4 acc[2][2] = {};
  for (int kk = 0; kk < 256; kk += 32) {
    const int ko = kk + quad * 8;
    const float* xr0 = x + (size_t)(row0 + l16) * 256 + ko;
    const float* xr1 = x + (size_t)(row0 + 16 + l16) * 256 + ko;
    bf16x8 a0 = cvt8(*(const float4*)xr0, *(const float4*)(xr0 + 4));
    bf16x8 a1 = cvt8(*(const float4*)xr1, *(const float4*)(xr1 + 4));
    bf16x8 b0 = *(const bf16x8*)(Wt + (size_t)(c0 + l16) * 256 + ko);
    bf16x8 b1 = *(const bf16x8*)(Wt + (size_t)(c0 + 16 + l16) * 256 + ko);
    acc[0][0] = MFMA16(a0, b0, acc[0][0]);
    acc[0][1] = MFMA16(a0, b1, acc[0][1]);
    acc[1][0] = MFMA16(a1, b0, acc[1][0]);
    acc[1][1] = MFMA16(a1, b1, acc[1][1]);
  }
  if (ct < 4) {
#pragma unroll
    for (int mt = 0; mt < 2; ++mt)
#pragma unroll
      for (int nt = 0; nt < 2; ++nt) {
        const int m8 = wr * 4 + mt * 2 + (quad >> 1);
        const int d  = wc * 32 + nt * 16 + l16;
        bf16x4 o;
        o.x = (__bf16)acc[mt][nt][0];
        o.y = (__bf16)acc[mt][nt][1];
        o.z = (__bf16)acc[mt][nt][2];
        o.w = (__bf16)acc[mt][nt][3];
        *(bf16x4*)(&vs[m8 * 512 + d * 8 + (quad & 1) * 4]) = o;
      }
    __syncthreads();
    const int m8 = t >> 5, s32 = t & 31;
    const int bat = rbk >> 6, mc = rbk & 63;
    bf16x8 a = *(const bf16x8*)(&vs[m8 * 512 + s32 * 16]);
    bf16x8 b = *(const bf16x8*)(&vs[m8 * 512 + s32 * 16 + 8]);
    __bf16* dst = Vt + (size_t)bat * 1048576 + (size_t)mc * 16384 +
                  m8 * 2048 + ct * 512 + s32 * 16;
    *(bf16x8*)dst       = a;
    *(bf16x8*)(dst + 8) = b;
  } else {
    float* dstb = (ct == 4) ? lbuf : rbuf;
#pragma unroll
    for (int mt = 0; mt < 2; ++mt)
#pragma unroll
      for (int nt = 0; nt < 2; ++nt) {
        const int col = c0 + nt * 16 + l16;
        const int gr  = rbk * 64 + wr * 32 + mt * 16 + quad * 4;
#pragma unroll
        for (int rr = 0; rr < 4; ++rr)
          dstb[(size_t)(gr + rr) * 64 + col] = acc[mt][nt][rr];
      }
  }
}

// ================= phase 2: attention GEMM block (bid 0..511)
// TM=64, TN=256, split-K=4 (32 chunks of K=32); 3-buffer counted-vmcnt
// pipeline, depth 2, vmcnt(8) steady (never 0 in the loop). LDS 53.5 KB.
__device__ void dev_attn(int bid, int t, char* smem_, const float* __restrict__ lbuf,
                         const float* __restrict__ rbuf, const __bf16* __restrict__ Vt,
                         __bf16* __restrict__ part, float* __restrict__ zpart) {
  __bf16* vb0 = (__bf16*)smem_;
  __bf16* vb1 = (__bf16*)(smem_ + 16384);
  __bf16* vb2 = (__bf16*)(smem_ + 32768);
  float*  ls  = (float*)(smem_ + 49152);       // [64][17]
  const int lane = t & 63, w = t >> 6;
  const int l16 = lane & 15, quad = lane >> 4;
  const int wr = w >> 1, wc = w & 1;           // 2 row-waves x 2 col-waves
  const int cmb = bid & 7;
  const int sp  = cmb >> 1;
  const int bat = cmb & 1;
  const int rbl = bid >> 3;
  const int g0  = bat * 4096 + rbl * 64;
  const __bf16* Vbase = Vt + (size_t)bat * 1048576;
  const int ck0 = sp * 32;

  {
    const int row = t >> 2, c = (t & 3) * 4;
    f32x4 v = *(const f32x4*)(lbuf + (size_t)(g0 + row) * 64 + sp * 16 + c);
    ls[row * 17 + c + 0] = v[0];
    ls[row * 17 + c + 1] = v[1];
    ls[row * 17 + c + 2] = v[2];
    ls[row * 17 + c + 3] = v[3];
  }
  const float LOG2E = 1.44269504088896f;
  float rreg[2][16];
#pragma unroll
  for (int mt = 0; mt < 2; ++mt) {
    const float* rp = rbuf + (size_t)(g0 + wr * 32 + mt * 16 + l16) * 64;
    f32x4 a = *(const f32x4*)(rp + quad * 8);
    f32x4 b = *(const f32x4*)(rp + quad * 8 + 4);
    f32x4 c = *(const f32x4*)(rp + 32 + quad * 8);
    f32x4 d = *(const f32x4*)(rp + 32 + quad * 8 + 4);
#pragma unroll
    for (int j = 0; j < 4; ++j) {
      rreg[mt][j]      = a[j] * LOG2E;
      rreg[mt][4 + j]  = b[j] * LOG2E;
      rreg[mt][8 + j]  = c[j] * LOG2E;
      rreg[mt][12 + j] = d[j] * LOG2E;
    }
  }

  f32x4 acc[2][8] = {};
  float zacc[2][2] = {{0.f, 0.f}, {0.f, 0.f}};

#define STAGE(KC, DST)                                                          \
  {                                                                             \
    const __bf16* src = Vbase + (size_t)(ck0 + (KC)) * 8192;                    \
    _Pragma("unroll")                                                           \
    for (int i = 0; i < 4; ++i)                                                 \
      gll16(src + (size_t)(i * 256 + t) * 8, (DST) + (i * 256 + (w << 6)) * 8); \
  }

#define AF_COMPUTE(KC)                                                        \
  {                                                                           \
    const int c16 = (KC) >> 1, hf = ((KC) & 1) * 8;                           \
    _Pragma("unroll")                                                         \
    for (int mt = 0; mt < 2; ++mt) {                                          \
      const float lv = ls[(wr * 32 + mt * 16 + l16) * 17 + c16];              \
      _Pragma("unroll")                                                       \
      for (int j = 0; j < 8; ++j) {                                           \
        const float e = fast_exp2(lv * rreg[mt][hf + j]);                     \
        zacc[mt][(KC) & 1] += e;                                              \
        af[mt][j] = (__bf16)e;                                                \
      }                                                                       \
    }                                                                         \
  }

#define MFMA_PHASE(CUR)                                                       \
  {                                                                           \
    _Pragma("unroll")                                                         \
    for (int nt = 0; nt < 8; ++nt) {                                          \
      bf16x8 bv = *(const bf16x8*)((CUR) + quad * 2048 +                      \
                                   (wc * 128 + nt * 16 + l16) * 8);           \
      acc[0][nt] = MFMA16(af[0], bv, acc[0][nt]);                             \
      acc[1][nt] = MFMA16(af[1], bv, acc[1][nt]);                             \
    }                                                                         \
  }

#define STEP(CC, BCUR, SC, BST, VM)                                           \
  {                                                                           \
    STAGE(SC, BST);                                                           \
    bf16x8 af[2];                                                             \
    AF_COMPUTE(CC);                                                           \
    asm volatile("s_waitcnt vmcnt(" #VM ")" ::: "memory");                    \
    __builtin_amdgcn_s_barrier();                                             \
    __builtin_amdgcn_sched_barrier(0);                                        \
    MFMA_PHASE(BCUR);                                                         \
    __builtin_amdgcn_s_barrier();                                             \
    __builtin_amdgcn_sched_barrier(0);                                        \
  }

#define STEPX(CC, BCUR, VM)                                                   \
  {                                                                           \
    bf16x8 af[2];                                                             \
    AF_COMPUTE(CC);                                                           \
    asm volatile("s_waitcnt vmcnt(" #VM ")" ::: "memory");                    \
    __builtin_amdgcn_s_barrier();                                             \
    __builtin_amdgcn_sched_barrier(0);                                        \
    MFMA_PHASE(BCUR);                                                         \
    __builtin_amdgcn_s_barrier();                                             \
    __builtin_amdgcn_sched_barrier(0);                                        \
  }

  // prologue: chunks 0,1 staged; the only full drain in the loop
  STAGE(0, vb0);
  STAGE(1, vb1);
  __syncthreads();

  // steady: chunk k lives in vb[k%3]; prefetch distance 2 -> vmcnt(8)
  for (int c = 0; c < 30; c += 3) {
    STEP(c + 0, vb0, c + 2, vb2, 8);
    STEP(c + 1, vb1, c + 3, vb0, 8);
    STEP(c + 2, vb2, c + 4, vb1, 8);
  }
  STEPX(30, vb0, 4);
  STEPX(31, vb1, 0);

#undef STAGE
#undef AF_COMPUTE
#undef MFMA_PHASE
#undef STEP
#undef STEPX

#pragma unroll
  for (int mt = 0; mt < 2; ++mt) {
    float z = zacc[mt][0] + zacc[mt][1];
    z += __shfl_xor(z, 16);
    z += __shfl_xor(z, 32);
    if (wc == 0 && quad == 0)
      zpart[(size_t)sp * 8192 + g0 + wr * 32 + mt * 16 + l16] = z;
  }

  __syncthreads();
  __bf16* ctile = (__bf16*)smem_;              // 64x264 bf16 = 33.8 KB, fits
#pragma unroll
  for (int mt = 0; mt < 2; ++mt)
#pragma unroll
    for (int nt = 0; nt < 8; ++nt) {
      const int r0 = wr * 32 + mt * 16 + quad * 4;
      const int c  = wc * 128 + nt * 16 + l16;
#pragma unroll
      for (int rr = 0; rr < 4; ++rr)
        ctile[(r0 + rr) * 264 + c] = (__bf16)acc[mt][nt][rr];
    }
  __syncthreads();
  __bf16* pb = part + (size_t)sp * (8192 * 256);
#pragma unroll
  for (int p = 0; p < 8; ++p) {
    const int u = p * 256 + t;
    const int row = u >> 5, seg = u & 31;
    *(bf16x8*)(pb + (size_t)(g0 + row) * 256 + seg * 8) =
        *(const bf16x8*)(ctile + row * 264 + seg * 8);
  }
}

// ================= phase 3: out = (sum_s part[s]) / Z (streaming)
__device__ __forceinline__ void dev_fix(int idx, const __bf16* __restrict__ part,
                                        const float* __restrict__ zpart,
                                        float* __restrict__ out) {
  const int g = idx >> 5, seg = idx & 31;
  float z = 0.f;
#pragma unroll
  for (int s = 0; s < 4; ++s) z += zpart[(size_t)s * 8192 + g];
  const float iz = 1.0f / z;
  float sum[8] = {};
#pragma unroll
  for (int s = 0; s < 4; ++s) {
    bf16x8 p = *(const bf16x8*)(part + (size_t)s * (8192 * 256) + (size_t)g * 256 + seg * 8);
#pragma unroll
    for (int j = 0; j < 8; ++j) sum[j] += (float)p[j];
  }
  f32x4 o0, o1;
#pragma unroll
  for (int j = 0; j < 4; ++j) { o0[j] = sum[j] * iz; o1[j] = sum[4 + j] * iz; }
  float* dst = out + (size_t)g * 256 + seg * 8;
  *(f32x4*)dst       = o0;
  *(f32x4*)(dst + 4) = o1;
}

// ================= fused mega-kernel: plain launch + software grid barriers
__global__ __launch_bounds__(256, 2) void k_mega(const float* __restrict__ x,
                                                 const float* __restrict__ Wl,
                                                 const float* __restrict__ Wr,
                                                 const float* __restrict__ Wv,
                                                 const float* __restrict__ Wo,
                                                 __bf16* Wvt, __bf16* Wlt, __bf16* Wrt,
                                                 __bf16* Vt, float* lbuf, float* rbuf,
                                                 __bf16* part, float* zpart, float* out,
                                                 unsigned* bar) {
  __shared__ __align__(16) char smem[53504];
  const int bid = blockIdx.x;                    // 0..511
  const int t   = threadIdx.x;                   // 0..255

  // phase 0: weight prep (blocks 288..511 pass straight to the barrier)
  if (bid < 256)      dev_wvo(bid, t, Wv, Wo, Wvt);
  else if (bid < 288) dev_tr((bid - 256) * 1024, t, Wl, Wr, Wlt, Wrt);
  gbar(bar + 0, 512);

  // phase 1: projections, 768 units (bid<256 do two; unit%8 == bid%8 both times)
  dev_proj(bid, t, smem, x, Wvt, Wlt, Wrt, Vt, lbuf, rbuf);
  if (bid < 256) dev_proj(512 + bid, t, smem, x, Wvt, Wlt, Wrt, Vt, lbuf, rbuf);
  gbar(bar + 16, 512);

  // phase 2: attention GEMM
  dev_attn(bid, t, smem, lbuf, rbuf, Vt, part, zpart);
  gbar(bar + 32, 512);

  // phase 3: fixup (2 units/block cover all 262144)
  dev_fix(bid * 256 + t, part, zpart, out);
  dev_fix((512 + bid) * 256 + t, part, zpart, out);
}

extern "C" void kernel_launch(void* const* d_in, const int* in_sizes, int n_in,
                              void* d_out, int out_size, void* d_ws, size_t ws_size,
                              hipStream_t stream) {
  const float* x  = (const float*)d_in[0];
  const float* Wl = (const float*)d_in[1];
  const float* Wr = (const float*)d_in[2];
  const float* Wv = (const float*)d_in[3];
  const float* Wo = (const float*)d_in[4];
  char* ws = (char*)d_ws;
  __bf16* Wvt = (__bf16*)(ws + OFF_WVT);
  __bf16* Wlt = (__bf16*)(ws + OFF_WLT);
  __bf16* Wrt = (__bf16*)(ws + OFF_WRT);
  __bf16* Vt  = (__bf16*)(ws + OFF_VT);
  float*  lb  = (float*)(ws + OFF_L);
  float*  rbf = (float*)(ws + OFF_R);
  __bf16* prt = (__bf16*)(ws + OFF_PART);
  float*  zp  = (float*)(ws + OFF_ZP);
  unsigned* bar = (unsigned*)(ws + OFF_BAR);
  float*  out = (float*)d_out;

  // ws is poisoned between calls; zero the barrier counters (capture-legal).
  hipMemsetAsync(bar, 0, 256, stream);
  k_mega<<<512, 256, 0, stream>>>(x, Wl, Wr, Wv, Wo, Wvt, Wlt, Wrt, Vt,
                                  lb, rbf, prt, zp, out, bar);
}

// Round 9
// 179.118 us; speedup vs baseline: 1.6168x; 1.6168x over previous
//
#include <hip/hip_runtime.h>
#include <hip/hip_bf16.h>

typedef __attribute__((ext_vector_type(8))) __bf16 bf16x8;
typedef __attribute__((ext_vector_type(4))) __bf16 bf16x4;
typedef __attribute__((ext_vector_type(4))) float  f32x4;

#define MFMA16(a, b, c) __builtin_amdgcn_mfma_f32_16x16x32_bf16((a), (b), (c), 0, 0, 0)

// B=2, S=4096, D=256, P=R=64. Flattened rows g = b*4096 + n (8192 total).
// Wo folded into Wv: Wvo = Wv @ Wo -> attention partials are pre-scale output.
static constexpr size_t OFF_WVT  = 0;                        // bf16 [256][256] (Wvo^T, [n][k])
static constexpr size_t OFF_WLT  = OFF_WVT + 256 * 256 * 2;  // bf16 [64][256]
static constexpr size_t OFF_WRT  = OFF_WLT + 64 * 256 * 2;   // bf16 [64][256]
static constexpr size_t OFF_VT   = 1u << 20;                 // bf16 [2][64][8][256][8] packed V', 4 MiB
static constexpr size_t OFF_L    = 6u << 20;                 // f32  [8192][64]  2 MiB
static constexpr size_t OFF_R    = 8u << 20;                 // f32  [8192][64]  2 MiB
static constexpr size_t OFF_PART = 10u << 20;                // bf16 [8][8192][256] 32 MiB
static constexpr size_t OFF_ZP   = 43u << 20;                // f32  [8][8192]   256 KiB

__device__ __forceinline__ float fast_exp2(float x) {
  float e;
  asm("v_exp_f32 %0, %1" : "=v"(e) : "v"(x));
  return e;
}

__device__ __forceinline__ bf16x8 cvt8(float4 a, float4 b) {
  bf16x8 o;
  o[0] = (__bf16)a.x; o[1] = (__bf16)a.y; o[2] = (__bf16)a.z; o[3] = (__bf16)a.w;
  o[4] = (__bf16)b.x; o[5] = (__bf16)b.y; o[6] = (__bf16)b.z; o[7] = (__bf16)b.w;
  return o;
}

// async global->LDS, 16B/lane; lds dst is the wave-uniform base (HW adds 16*lane).
__device__ __forceinline__ void gll16(const __bf16* g, __bf16* l) {
  __builtin_amdgcn_global_load_lds((const __attribute__((address_space(1))) void*)g,
                                   (__attribute__((address_space(3))) void*)l,
                                   16, 0, 0);
}

// ---------------- weight prep: Wl/Wr transpose to [n][k] bf16; Wvt = (Wv@Wo)^T bf16
// (R6 version: 1024 thr, 4-way j-split + LDS reduce for the Wvo dot)
__global__ __launch_bounds__(1024) void k_prepw(const float* __restrict__ Wv,
                                                const float* __restrict__ Wl,
                                                const float* __restrict__ Wr,
                                                const float* __restrict__ Wo,
                                                __bf16* __restrict__ Wvt,
                                                __bf16* __restrict__ Wlt,
                                                __bf16* __restrict__ Wrt) {
  __shared__ float red[3][256];
  const int blk = blockIdx.x;
  const int t = threadIdx.x;
  if (blk < 32) {
    const int idx = blk * 1024 + t;              // 0 .. 32767
    if (idx < 16384) {
      const int k = idx >> 6, n = idx & 63;
      Wlt[n * 256 + k] = (__bf16)Wl[idx];
    } else {
      const int j = idx - 16384;
      const int k = j >> 6, n = j & 63;
      Wrt[n * 256 + k] = (__bf16)Wr[j];
    }
  } else {
    const int k  = blk - 32;                     // 0..255
    const int n  = t & 255;
    const int jq = t >> 8;                       // 0..3
    const float* wvr = Wv + (size_t)k * 256 + jq * 64;
    const float* wor = Wo + (size_t)(jq * 64) * 256 + n;
    float a0 = 0.f, a1 = 0.f, a2 = 0.f, a3 = 0.f;
#pragma unroll 4
    for (int j = 0; j < 64; j += 4) {
      a0 += wvr[j + 0] * wor[(size_t)(j + 0) * 256];
      a1 += wvr[j + 1] * wor[(size_t)(j + 1) * 256];
      a2 += wvr[j + 2] * wor[(size_t)(j + 2) * 256];
      a3 += wvr[j + 3] * wor[(size_t)(j + 3) * 256];
    }
    const float s = (a0 + a1) + (a2 + a3);
    if (jq > 0) red[jq - 1][n] = s;
    __syncthreads();
    if (jq == 0)
      Wvt[(size_t)n * 256 + k] = (__bf16)(s + red[0][n] + red[1][n] + red[2][n]);
  }
}

// --------- projections: V' packed [bat][chunk][m8][d][j] (bf16), l, r (fp32)
// grid 768 linear, XCD-swizzled: all 6 ct-tiles of a given rbk share id%8.
__global__ __launch_bounds__(256) void k_proj(const float* __restrict__ x,
                                              const __bf16* __restrict__ Wvt,
                                              const __bf16* __restrict__ Wlt,
                                              const __bf16* __restrict__ Wrt,
                                              __bf16* __restrict__ Vt,
                                              float* __restrict__ lbuf,
                                              float* __restrict__ rbuf) {
  __shared__ __align__(16) __bf16 vs[8 * 64 * 8];  // [m8][d_local][j]
  const int t = threadIdx.x;
  const int lane = t & 63, wave = t >> 6;
  const int l16 = lane & 15, quad = lane >> 4;
  const int wr = wave >> 1, wc = wave & 1;
  const int bid = blockIdx.x;
  const int q   = bid / 48;
  const int rmd = bid - q * 48;
  const int ct  = rmd >> 3;
  const int rbk = q * 8 + (rmd & 7);
  const __bf16* Wt;
  int colbase;
  if (ct < 4)       { Wt = Wvt; colbase = ct * 64; }
  else if (ct == 4) { Wt = Wlt; colbase = 0; }
  else              { Wt = Wrt; colbase = 0; }
  const int row0 = rbk * 64 + wr * 32;
  const int c0   = colbase + wc * 32;
  f32x4 acc[2][2] = {};
  for (int kk = 0; kk < 256; kk += 32) {
    const int ko = kk + quad * 8;
    const float* xr0 = x + (size_t)(row0 + l16) * 256 + ko;
    const float* xr1 = x + (size_t)(row0 + 16 + l16) * 256 + ko;
    bf16x8 a0 = cvt8(*(const float4*)xr0, *(const float4*)(xr0 + 4));
    bf16x8 a1 = cvt8(*(const float4*)xr1, *(const float4*)(xr1 + 4));
    bf16x8 b0 = *(const bf16x8*)(Wt + (size_t)(c0 + l16) * 256 + ko);
    bf16x8 b1 = *(const bf16x8*)(Wt + (size_t)(c0 + 16 + l16) * 256 + ko);
    acc[0][0] = MFMA16(a0, b0, acc[0][0]);
    acc[0][1] = MFMA16(a0, b1, acc[0][1]);
    acc[1][0] = MFMA16(a1, b0, acc[1][0]);
    acc[1][1] = MFMA16(a1, b1, acc[1][1]);
  }
  if (ct < 4) {
#pragma unroll
    for (int mt = 0; mt < 2; ++mt)
#pragma unroll
      for (int nt = 0; nt < 2; ++nt) {
        const int m8 = wr * 4 + mt * 2 + (quad >> 1);
        const int d  = wc * 32 + nt * 16 + l16;
        bf16x4 o;
        o.x = (__bf16)acc[mt][nt][0];
        o.y = (__bf16)acc[mt][nt][1];
        o.z = (__bf16)acc[mt][nt][2];
        o.w = (__bf16)acc[mt][nt][3];
        *(bf16x4*)(&vs[m8 * 512 + d * 8 + (quad & 1) * 4]) = o;
      }
    __syncthreads();
    const int m8 = t >> 5, s32 = t & 31;
    const int bat = rbk >> 6, mc = rbk & 63;
    bf16x8 a = *(const bf16x8*)(&vs[m8 * 512 + s32 * 16]);
    bf16x8 b = *(const bf16x8*)(&vs[m8 * 512 + s32 * 16 + 8]);
    __bf16* dst = Vt + (size_t)bat * 1048576 + (size_t)mc * 16384 +
                  m8 * 2048 + ct * 512 + s32 * 16;
    *(bf16x8*)dst       = a;
    *(bf16x8*)(dst + 8) = b;
  } else {
    float* dstb = (ct == 4) ? lbuf : rbuf;
#pragma unroll
    for (int mt = 0; mt < 2; ++mt)
#pragma unroll
      for (int nt = 0; nt < 2; ++nt) {
        const int col = c0 + nt * 16 + l16;
        const int gr  = rbk * 64 + wr * 32 + mt * 16 + quad * 4;
#pragma unroll
        for (int rr = 0; rr < 4; ++rr)
          dstb[(size_t)(gr + rr) * 64 + col] = acc[mt][nt][rr];
      }
  }
}

// ---------------- main attention GEMM: part_s = P_s @ V' (unnormalized), Z_s
// grid 1024 x 256thr: TM=64, TN=256, split-K=8 (16 chunks of K=32).
// Occupancy is the lever this round: LDS 51.5 KB + launch_bounds(256,3)
// -> THREE blocks/CU = 12 waves/CU (all prior variants ran 8 waves/CU and
// all landed 27-29 us -> stall-bound, not schedule-bound).
// 3-buffer counted-vmcnt pipeline, depth 2, vmcnt(8) steady. T5 setprio
// around the MFMA cluster (3 independent blocks/CU give role diversity).
__global__ __launch_bounds__(256, 3) void k_attn(const float* __restrict__ lbuf,
                                                 const float* __restrict__ rbuf,
                                                 const __bf16* __restrict__ Vt,
                                                 __bf16* __restrict__ part,
                                                 float* __restrict__ zpart) {
  __shared__ __align__(16) char smem[51456];   // vb[3][16KB] + ls[64][9]f32; epi ctile aliases
  __bf16* vb0 = (__bf16*)smem;
  __bf16* vb1 = (__bf16*)(smem + 16384);
  __bf16* vb2 = (__bf16*)(smem + 32768);
  float*  ls  = (float*)(smem + 49152);        // [64][9] (stride 9 -> <=2-way conflicts, free)
  const int t = threadIdx.x;                   // 0..255
  const int lane = t & 63, w = t >> 6;
  const int l16 = lane & 15, quad = lane >> 4;
  const int wr = w >> 1, wc = w & 1;           // 2 row-waves x 2 col-waves
  const int bid = blockIdx.x;                  // 0..1023
  const int cmb = bid & 15;
  const int sp  = cmb >> 1;                    // 0..7
  const int bat = cmb & 1;                     // 0..1
  const int rbl = bid >> 4;                    // 0..63
  const int g0  = bat * 4096 + rbl * 64;
  const __bf16* Vbase = Vt + (size_t)bat * 1048576;
  const int ck0 = sp * 16;                     // first K=32 chunk of this split

  // l tile: rows g0..+63, 8 64-blocks for this split (2 f32 per thread)
  {
    const int row = t >> 2, c2 = (t & 3) * 2;
    const float* lp = lbuf + (size_t)(g0 + row) * 64 + sp * 8 + c2;
    ls[row * 9 + c2]     = lp[0];
    ls[row * 9 + c2 + 1] = lp[1];
  }
  // r fragments pre-scaled by log2(e): rreg[mt][hf+j] = r[hf*4... quad*8+j (+32)]
  const float LOG2E = 1.44269504088896f;
  float rreg[2][16];
#pragma unroll
  for (int mt = 0; mt < 2; ++mt) {
    const float* rp = rbuf + (size_t)(g0 + wr * 32 + mt * 16 + l16) * 64;
    f32x4 a = *(const f32x4*)(rp + quad * 8);
    f32x4 b = *(const f32x4*)(rp + quad * 8 + 4);
    f32x4 c = *(const f32x4*)(rp + 32 + quad * 8);
    f32x4 d = *(const f32x4*)(rp + 32 + quad * 8 + 4);
#pragma unroll
    for (int j = 0; j < 4; ++j) {
      rreg[mt][j]      = a[j] * LOG2E;
      rreg[mt][4 + j]  = b[j] * LOG2E;
      rreg[mt][8 + j]  = c[j] * LOG2E;
      rreg[mt][12 + j] = d[j] * LOG2E;
    }
  }

  f32x4 acc[2][8] = {};
  float zacc[2][2] = {{0.f, 0.f}, {0.f, 0.f}};

#define STAGE(KC, DST)                                                          \
  {                                                                             \
    const __bf16* src = Vbase + (size_t)(ck0 + (KC)) * 8192;                    \
    _Pragma("unroll")                                                           \
    for (int i = 0; i < 4; ++i)                                                 \
      gll16(src + (size_t)(i * 256 + t) * 8, (DST) + (i * 256 + (w << 6)) * 8); \
  }

#define AF_COMPUTE(KC)                                                        \
  {                                                                           \
    const int c16 = (KC) >> 1, hf = ((KC) & 1) * 8;                           \
    _Pragma("unroll")                                                         \
    for (int mt = 0; mt < 2; ++mt) {                                          \
      const float lv = ls[(wr * 32 + mt * 16 + l16) * 9 + c16];               \
      _Pragma("unroll")                                                       \
      for (int j = 0; j < 8; ++j) {                                           \
        const float e = fast_exp2(lv * rreg[mt][hf + j]);                     \
        zacc[mt][(KC) & 1] += e;                                              \
        af[mt][j] = (__bf16)e;                                                \
      }                                                                       \
    }                                                                         \
  }

#define MFMA_PHASE(CUR)                                                       \
  {                                                                           \
    __builtin_amdgcn_s_setprio(1);                                            \
    _Pragma("unroll")                                                         \
    for (int nt = 0; nt < 8; ++nt) {                                          \
      bf16x8 bv = *(const bf16x8*)((CUR) + quad * 2048 +                      \
                                   (wc * 128 + nt * 16 + l16) * 8);           \
      acc[0][nt] = MFMA16(af[0], bv, acc[0][nt]);                             \
      acc[1][nt] = MFMA16(af[1], bv, acc[1][nt]);                             \
    }                                                                         \
    __builtin_amdgcn_s_setprio(0);                                            \
  }

#define STEP(CC, BCUR, SC, BST, VM)                                           \
  {                                                                           \
    STAGE(SC, BST);                                                           \
    bf16x8 af[2];                                                             \
    AF_COMPUTE(CC);                                                           \
    asm volatile("s_waitcnt vmcnt(" #VM ")" ::: "memory");                    \
    __builtin_amdgcn_s_barrier();                                             \
    __builtin_amdgcn_sched_barrier(0);                                        \
    MFMA_PHASE(BCUR);                                                         \
    __builtin_amdgcn_s_barrier();                                             \
    __builtin_amdgcn_sched_barrier(0);                                        \
  }

#define STEPX(CC, BCUR, VM)                                                   \
  {                                                                           \
    bf16x8 af[2];                                                             \
    AF_COMPUTE(CC);                                                           \
    asm volatile("s_waitcnt vmcnt(" #VM ")" ::: "memory");                    \
    __builtin_amdgcn_s_barrier();                                             \
    __builtin_amdgcn_sched_barrier(0);                                        \
    MFMA_PHASE(BCUR);                                                         \
    __builtin_amdgcn_s_barrier();                                             \
    __builtin_amdgcn_sched_barrier(0);                                        \
  }

  // prologue: chunks 0,1 staged; the only full drain in the loop
  STAGE(0, vb0);
  STAGE(1, vb1);
  __syncthreads();

  // steady: chunk k lives in vb[k%3]; prefetch distance 2 -> vmcnt(8)
  for (int c = 0; c < 12; c += 3) {
    STEP(c + 0, vb0, c + 2, vb2, 8);
    STEP(c + 1, vb1, c + 3, vb0, 8);
    STEP(c + 2, vb2, c + 4, vb1, 8);
  }
  STEP (12, vb0, 14, vb2, 8);
  STEP (13, vb1, 15, vb0, 8);
  STEPX(14, vb2, 4);
  STEPX(15, vb0, 0);

#undef STAGE
#undef AF_COMPUTE
#undef MFMA_PHASE
#undef STEP
#undef STEPX

  // Z partials (both col-waves hold identical z; col-wave 0 owns the write)
#pragma unroll
  for (int mt = 0; mt < 2; ++mt) {
    float z = zacc[mt][0] + zacc[mt][1];
    z += __shfl_xor(z, 16);
    z += __shfl_xor(z, 32);
    if (wc == 0 && quad == 0)
      zpart[(size_t)sp * 8192 + g0 + wr * 32 + mt * 16 + l16] = z;
  }

  // epilogue: stage C tile (64x256 bf16, stride 264 = 33.8 KB) in LDS
  __syncthreads();                 // all LDS reads done before aliasing
  __bf16* ctile = (__bf16*)smem;
#pragma unroll
  for (int mt = 0; mt < 2; ++mt)
#pragma unroll
    for (int nt = 0; nt < 8; ++nt) {
      const int r0 = wr * 32 + mt * 16 + quad * 4;
      const int c  = wc * 128 + nt * 16 + l16;
#pragma unroll
      for (int rr = 0; rr < 4; ++rr)
        ctile[(r0 + rr) * 264 + c] = (__bf16)acc[mt][nt][rr];
    }
  __syncthreads();
  __bf16* pb = part + (size_t)sp * (8192 * 256);
#pragma unroll
  for (int p = 0; p < 8; ++p) {
    const int u = p * 256 + t;
    const int row = u >> 5, seg = u & 31;
    *(bf16x8*)(pb + (size_t)(g0 + row) * 256 + seg * 8) =
        *(const bf16x8*)(ctile + row * 264 + seg * 8);
  }
}

// ------- final fixup: out = (sum_s part[s]) / Z  (pure streaming, 8 splits)
__global__ __launch_bounds__(256) void k_fix(const __bf16* __restrict__ part,
                                             const float* __restrict__ zpart,
                                             float* __restrict__ out) {
  const int idx = blockIdx.x * 256 + threadIdx.x;   // 0 .. 262143
  const int g = idx >> 5, seg = idx & 31;
  float z = 0.f;
#pragma unroll
  for (int s = 0; s < 8; ++s) z += zpart[(size_t)s * 8192 + g];
  const float iz = 1.0f / z;
  float sum[8] = {};
#pragma unroll
  for (int s = 0; s < 8; ++s) {
    bf16x8 p = *(const bf16x8*)(part + (size_t)s * (8192 * 256) + (size_t)g * 256 + seg * 8);
#pragma unroll
    for (int j = 0; j < 8; ++j) sum[j] += (float)p[j];
  }
  f32x4 o0, o1;
#pragma unroll
  for (int j = 0; j < 4; ++j) { o0[j] = sum[j] * iz; o1[j] = sum[4 + j] * iz; }
  float* dst = out + (size_t)g * 256 + seg * 8;
  *(f32x4*)dst       = o0;
  *(f32x4*)(dst + 4) = o1;
}

extern "C" void kernel_launch(void* const* d_in, const int* in_sizes, int n_in,
                              void* d_out, int out_size, void* d_ws, size_t ws_size,
                              hipStream_t stream) {
  const float* x  = (const float*)d_in[0];
  const float* Wl = (const float*)d_in[1];
  const float* Wr = (const float*)d_in[2];
  const float* Wv = (const float*)d_in[3];
  const float* Wo = (const float*)d_in[4];
  char* ws = (char*)d_ws;
  __bf16* Wvt = (__bf16*)(ws + OFF_WVT);
  __bf16* Wlt = (__bf16*)(ws + OFF_WLT);
  __bf16* Wrt = (__bf16*)(ws + OFF_WRT);
  __bf16* Vt  = (__bf16*)(ws + OFF_VT);
  float*  lb  = (float*)(ws + OFF_L);
  float*  rbf = (float*)(ws + OFF_R);
  __bf16* prt = (__bf16*)(ws + OFF_PART);
  float*  zp  = (float*)(ws + OFF_ZP);
  float*  out = (float*)d_out;

  k_prepw<<<288, 1024, 0, stream>>>(Wv, Wl, Wr, Wo, Wvt, Wlt, Wrt);
  k_proj<<<768, 256, 0, stream>>>(x, Wvt, Wlt, Wrt, Vt, lb, rbf);
  k_attn<<<1024, 256, 0, stream>>>(lb, rbf, Vt, prt, zp);
  k_fix<<<1024, 256, 0, stream>>>(prt, zp, out);
}